// Round 4
// baseline (23567.557 us; speedup 1.0000x reference)
//
#include <hip/hip_runtime.h>
#include <hip/hip_bf16.h>
#include <cstdint>

// MixTransformer: B=2,S=1024,D=2048,H=16,KVH=8,HD=128,DFF=8192,E=8,K=2,R=16
// Round 4: runtime dtype detection (inputs may be f32 or bf16). f32-fidelity
// attention path via hi/lo-split bf16 MFMA (A and W both split, 3 passes).
// Dense-expert MoE (no data-dependent addressing). Output dtype flag-dispatched.

typedef __hip_bfloat16 bf16;
typedef unsigned short u16;
typedef unsigned int u32;
typedef __attribute__((ext_vector_type(8))) short short8;
typedef __attribute__((ext_vector_type(4))) float floatx4;

#define NT 2048      // B*S
#define DMODEL 2048
#define DFF 8192
#define NH 512       // rows per MoE quarter-batch

__device__ __forceinline__ float ldin(const void* p, size_t i, int isf){
  return isf ? ((const float*)p)[i] : __bfloat162float(((const bf16*)p)[i]);
}
__device__ __forceinline__ u16 f2bu(float v){ bf16 h = __float2bfloat16(v); return *(u16*)&h; }
__device__ __forceinline__ float bu2f(u16 v){ u32 x = ((u32)v) << 16; return __uint_as_float(x); }

// ---------------- dtype detection: cos[0] == 1.0f ----------------
__global__ void detect_k(const void* __restrict__ cosp, int* __restrict__ flag){
  if (threadIdx.x == 0 && blockIdx.x == 0){
    u32 w = *(const u32*)cosp;
    flag[0] = (w == 0x3F800000u) ? 1 : 0;   // 1 = float32 inputs, 0 = bf16
  }
}

// ---------------- RMSNorm producing hi/lo bf16 split ----------------
__global__ __launch_bounds__(256) void rmsnorm_split(const int* __restrict__ flagp,
                                                     const void* __restrict__ x, const void* __restrict__ w,
                                                     bf16* __restrict__ hi, bf16* __restrict__ lo){
  int isf = flagp[0];
  int row = blockIdx.x; int tid = threadIdx.x;
  float ss = 0.f;
  for (int d = tid; d < DMODEL; d += 256){ float v = ldin(x, (size_t)row * DMODEL + d, isf); ss = fmaf(v, v, ss); }
  __shared__ float red[256];
  red[tid] = ss; __syncthreads();
  for (int s = 128; s > 0; s >>= 1){ if (tid < s) red[tid] += red[tid + s]; __syncthreads(); }
  float m = red[0] / (float)DMODEL + 1e-5f;
  float r = rsqrtf(m); r = r * (1.5f - 0.5f * m * r * r);  // Newton refine
  for (int d = tid; d < DMODEL; d += 256){
    float v = ldin(x, (size_t)row * DMODEL + d, isf) * r * ldin(w, d, isf);
    bf16 vh = __float2bfloat16(v);
    hi[(size_t)row * DMODEL + d] = vh;
    lo[(size_t)row * DMODEL + d] = __float2bfloat16(v - __bfloat162float(vh));
  }
}

// ---------------- RMSNorm f32 -> bf16 ----------------
__global__ __launch_bounds__(256) void rmsnorm_f32(const int* __restrict__ flagp,
                                                   const float* __restrict__ x, const void* __restrict__ w,
                                                   bf16* __restrict__ out){
  int isf = flagp[0];
  int row = blockIdx.x; int tid = threadIdx.x;
  const float* xr = x + (size_t)row * DMODEL;
  float ss = 0.f;
  for (int d = tid; d < DMODEL; d += 256){ float v = xr[d]; ss = fmaf(v, v, ss); }
  __shared__ float red[256];
  red[tid] = ss; __syncthreads();
  for (int s = 128; s > 0; s >>= 1){ if (tid < s) red[tid] += red[tid + s]; __syncthreads(); }
  float m = red[0] / (float)DMODEL + 1e-5f;
  float r = rsqrtf(m); r = r * (1.5f - 0.5f * m * r * r);
  for (int d = tid; d < DMODEL; d += 256)
    out[(size_t)row * DMODEL + d] = __float2bfloat16(xr[d] * r * ldin(w, d, isf));
}

// ---------------- Gate logits in f64 (routing precision) ----------------
__global__ __launch_bounds__(256) void logits_k(const int* __restrict__ flagp,
                                                const float* __restrict__ x, const void* __restrict__ w,
                                                const void* __restrict__ gw, float* __restrict__ out){
  int isf = flagp[0];
  int row = blockIdx.x; int tid = threadIdx.x;
  const float* xr = x + (size_t)row * DMODEL;
  __shared__ double red[256];
  double ss = 0.0;
  for (int d = tid; d < DMODEL; d += 256){ double v = xr[d]; ss += v * v; }
  red[tid] = ss; __syncthreads();
  for (int s = 128; s > 0; s >>= 1){ if (tid < s) red[tid] += red[tid + s]; __syncthreads(); }
  double scale = 1.0 / sqrt(red[0] / (double)DMODEL + 1e-5);
  double acc[8] = {0,0,0,0,0,0,0,0};
  for (int d = tid; d < DMODEL; d += 256){
    double sv = (double)xr[d] * scale * (double)ldin(w, d, isf);
    #pragma unroll
    for (int e = 0; e < 8; e++) acc[e] += sv * (double)ldin(gw, (size_t)d * 8 + e, isf);
  }
  __shared__ double red8[256][8];
  #pragma unroll
  for (int e = 0; e < 8; e++) red8[tid][e] = acc[e];
  __syncthreads();
  for (int s = 128; s > 0; s >>= 1){
    if (tid < s){ for (int e = 0; e < 8; e++) red8[tid][e] += red8[tid + s][e]; }
    __syncthreads();
  }
  if (tid < 8) out[row * 8 + tid] = (float)red8[0][tid];
}

// ---------------- Routing -> dense ew[NT][8] (0 for unselected) ----------------
__global__ void route_ew(const float* __restrict__ logits, float* __restrict__ ew){
  int row = blockIdx.x * 256 + threadIdx.x;
  if (row >= NT) return;
  float l[8]; float mx = -1e30f;
  for (int e = 0; e < 8; e++){ l[e] = logits[row * 8 + e]; mx = fmaxf(mx, l[e]); }
  float p[8];
  for (int e = 0; e < 8; e++) p[e] = expf(l[e] - mx);
  int e1 = 0; float b1v = p[0];
  for (int e = 1; e < 8; e++) if (p[e] > b1v){ b1v = p[e]; e1 = e; }
  int e2 = -1; float b2v = -1.f;
  for (int e = 0; e < 8; e++) if (e != e1 && p[e] > b2v){ b2v = p[e]; e2 = e; }
  float s = b1v + b2v;
  for (int e = 0; e < 8; e++){
    float w = 0.f;
    if (e == e1) w = b1v / s;
    else if (e == e2) w = b2v / s;
    ew[row * 8 + e] = w;
  }
}

__global__ void zero_f(float* __restrict__ p, int n){
  int i = blockIdx.x * 256 + threadIdx.x;
  if (i < n) p[i] = 0.f;
}
__global__ void fill_b(bf16* __restrict__ p, float v, int n){
  int i = blockIdx.x * 256 + threadIdx.x;
  if (i < n) p[i] = __float2bfloat16(v);
}

// ---------------- MFMA GEMM: C = A@W (+ hi/lo fidelity) [+ 2*lt@lB] ----------------
// A,A2: internal bf16 (A2 = lo part for fid=2). W: INPUT weights, dtype by flag.
// fid=2: acc += Ahi*Whi + Ahi*Wlo + Alo*Whi (Wlo on-the-fly split in f32 mode).
// fid=0: acc += A*Whi.
// mode 0: Cb=bf16(c); 1: Cf=c; 2: w=ew8[gm*8+eIdx]; if(w!=0) Cf += c*w
__global__ __launch_bounds__(256) void gemm_k(
    const int* __restrict__ flagp,
    const bf16* __restrict__ A, const bf16* __restrict__ A2, int lda,
    const void* __restrict__ W, long long wOff, int ldw,
    float* __restrict__ Cf, bf16* __restrict__ Cb, int ldc,
    int M, int N, int Kd,
    const float* __restrict__ lt, int ldt,
    const void* __restrict__ lB, long long lbOff, int ldlB,
    const float* __restrict__ ew8, int eIdx, int mode, int fid)
{
  int isf = flagp[0];
  int m0 = blockIdx.x * 64;
  int n0 = blockIdx.y * 64;
  if (m0 >= M) return;

  __shared__ __align__(16) u16 Ah[64][40], Al[64][40], Wh[64][40], Wl[64][40];

  int tid = threadIdx.x;
  int wv = tid >> 6, ln = tid & 63;
  int ar = tid >> 2, ac = (tid & 3) * 8;      // A staging: row ar, cols ac..ac+7
  int wr = tid >> 3, wc = (tid & 7) * 8;      // W staging: k-row wr, n-cols wc..wc+7
  int arow = m0 + ar; if (arow > M - 1) arow = M - 1;

  floatx4 acc[4];
  #pragma unroll
  for (int i = 0; i < 4; i++) acc[i] = (floatx4){0.f, 0.f, 0.f, 0.f};

  const float* Wf = (const float*)W + wOff;
  const bf16*  Wb = (const bf16*)W + wOff;

  for (int k0 = 0; k0 < Kd; k0 += 32){
    uint4 a1v = *(const uint4*)(A + (size_t)arow * lda + k0 + ac);
    uint4 a2v = (uint4){0,0,0,0};
    if (fid) a2v = *(const uint4*)(A2 + (size_t)arow * lda + k0 + ac);
    u16 whi[8], wlo[8];
    if (n0 + wc + 8 <= N){
      if (isf){
        const float* src = Wf + (size_t)(k0 + wr) * ldw + n0 + wc;
        #pragma unroll
        for (int j = 0; j < 8; j++){
          float v = src[j];
          u16 h = f2bu(v);
          whi[j] = h;
          wlo[j] = f2bu(v - bu2f(h));
        }
      } else {
        uint4 wv4 = *(const uint4*)(Wb + (size_t)(k0 + wr) * ldw + n0 + wc);
        const u16* ws = (const u16*)&wv4;
        #pragma unroll
        for (int j = 0; j < 8; j++){ whi[j] = ws[j]; wlo[j] = 0; }
      }
    } else {
      #pragma unroll
      for (int j = 0; j < 8; j++){ whi[j] = 0; wlo[j] = 0; }
    }
    __syncthreads();
    *(uint4*)&Ah[ar][ac] = a1v;
    if (fid) *(uint4*)&Al[ar][ac] = a2v;
    #pragma unroll
    for (int j = 0; j < 8; j++){
      Wh[wc + j][wr] = whi[j];
      if (fid) Wl[wc + j][wr] = wlo[j];
    }
    __syncthreads();
    short8 ah = *(const short8*)&Ah[wv * 16 + (ln & 15)][(ln >> 4) * 8];
    short8 al = ah;
    if (fid) al = *(const short8*)&Al[wv * 16 + (ln & 15)][(ln >> 4) * 8];
    #pragma unroll
    for (int nt = 0; nt < 4; nt++){
      short8 wh = *(const short8*)&Wh[nt * 16 + (ln & 15)][(ln >> 4) * 8];
      acc[nt] = __builtin_amdgcn_mfma_f32_16x16x32_bf16(ah, wh, acc[nt], 0, 0, 0);
      if (fid){
        short8 wl = *(const short8*)&Wl[nt * 16 + (ln & 15)][(ln >> 4) * 8];
        acc[nt] = __builtin_amdgcn_mfma_f32_16x16x32_bf16(ah, wl, acc[nt], 0, 0, 0);
        acc[nt] = __builtin_amdgcn_mfma_f32_16x16x32_bf16(al, wh, acc[nt], 0, 0, 0);
      }
    }
  }

  int rl = (ln >> 4) * 4;
  int cl = ln & 15;
  for (int nt = 0; nt < 4; nt++){
    int gn = n0 + nt * 16 + cl;
    if (gn >= N) continue;
    for (int i = 0; i < 4; i++){
      int gm = m0 + wv * 16 + rl + i;
      if (gm >= M) continue;
      float c = acc[nt][i];
      if (lt){
        const float* tr = lt + (size_t)gm * ldt;
        float l = 0.f;
        #pragma unroll
        for (int r = 0; r < 16; r++)
          l = fmaf(tr[r], ldin(lB, (size_t)(lbOff + (long long)r * ldlB + gn), isf), l);
        c += 2.0f * l;   // SCALING = 2.0
      }
      size_t ci = (size_t)gm * ldc + gn;
      if (mode == 0) Cb[ci] = __float2bfloat16(c);
      else if (mode == 1) Cf[ci] = c;
      else {
        float w = ew8[(size_t)gm * 8 + eIdx];
        if (w != 0.f) Cf[ci] += c * w;
      }
    }
  }
}

// ---------------- RoPE (f32, in place) ----------------
__global__ void rope_f32(const int* __restrict__ flagp, float* __restrict__ x,
                         const void* __restrict__ cosb, const void* __restrict__ sinb, int nHd){
  int isf = flagp[0];
  int idx = blockIdx.x * 256 + threadIdx.x;
  int d = idx & 63; int t = idx >> 6;
  int hh = t % nHd; t /= nHd;
  int s = t & 1023; int b = t >> 10;
  if (b >= 2) return;
  float* p = x + (((size_t)(b * 1024 + s)) * nHd + hh) * 128;
  float x1 = p[d], x2 = p[d + 64];
  float c1 = ldin(cosb, (size_t)s * 128 + d, isf);
  float s1 = ldin(sinb, (size_t)s * 128 + d, isf);
  float c2 = ldin(cosb, (size_t)s * 128 + d + 64, isf);
  float s2 = ldin(sinb, (size_t)s * 128 + d + 64, isf);
  p[d]      = x1 * c1 - x2 * s1;
  p[d + 64] = x2 * c2 + x1 * s2;
}

// ---------------- Flash attention, f32, causal, GQA; writes split-bf16 output ----
__global__ __launch_bounds__(256) void flash_attn(const float* __restrict__ xq, const float* __restrict__ xk,
                                                  const float* __restrict__ xv,
                                                  bf16* __restrict__ ohi, bf16* __restrict__ olo){
  __shared__ float TA[64][65];   // d 0..63   (K then V)
  __shared__ float TB[64][65];   // d 64..127
  __shared__ float qsh[16][128];
  int bid = blockIdx.x;
  int qb = bid & 63, h = (bid >> 6) & 15, b = bid >> 10;
  int q0 = qb * 16, kvh = h >> 1;
  int tid = threadIdx.x, wv = tid >> 6, ln = tid & 63;
  {
    int r = tid >> 4, d0 = (tid & 15) * 8;
    const float* src = xq + ((size_t)((b * 1024 + q0 + r) * 16 + h)) * 128 + d0;
    const float sc = 0.08838834764831845f;  // 1/sqrt(128)
    #pragma unroll
    for (int j = 0; j < 8; j++) qsh[r][d0 + j] = src[j] * sc;
  }
  float mr[4] = {-1e30f, -1e30f, -1e30f, -1e30f};
  float lr[4] = {0, 0, 0, 0}, o0[4] = {0, 0, 0, 0}, o1[4] = {0, 0, 0, 0};
  int r0 = wv * 4;
  int ntiles = q0 / 64 + 1;
  for (int t = 0; t < ntiles; t++){
    __syncthreads();
    {
      int j = tid >> 2, dc = (tid & 3) * 16;
      const float* ks = xk + ((size_t)((b * 1024 + t * 64 + j) * 8 + kvh)) * 128 + dc;
      #pragma unroll
      for (int i = 0; i < 16; i++){ TA[j][dc + i] = ks[i]; TB[j][dc + i] = ks[64 + i]; }
    }
    __syncthreads();
    float s0 = 0, s1 = 0, s2 = 0, s3 = 0;
    for (int d = 0; d < 64; d++){
      float kv = TA[ln][d];
      s0 = fmaf(qsh[r0][d], kv, s0);     s1 = fmaf(qsh[r0 + 1][d], kv, s1);
      s2 = fmaf(qsh[r0 + 2][d], kv, s2); s3 = fmaf(qsh[r0 + 3][d], kv, s3);
    }
    for (int d = 0; d < 64; d++){
      float kv = TB[ln][d];
      s0 = fmaf(qsh[r0][d + 64], kv, s0);     s1 = fmaf(qsh[r0 + 1][d + 64], kv, s1);
      s2 = fmaf(qsh[r0 + 2][d + 64], kv, s2); s3 = fmaf(qsh[r0 + 3][d + 64], kv, s3);
    }
    int key = t * 64 + ln;
    float sv[4] = {s0, s1, s2, s3};
    float pv4[4];
    #pragma unroll
    for (int rr = 0; rr < 4; rr++){
      int q = q0 + r0 + rr;
      float s = (key <= q) ? sv[rr] : -1e30f;
      float mt = s;
      #pragma unroll
      for (int of = 32; of; of >>= 1) mt = fmaxf(mt, __shfl_xor(mt, of));
      float mnew = fmaxf(mr[rr], mt);
      float p = __expf(s - mnew);
      float alpha = __expf(mr[rr] - mnew);
      float ps = p;
      #pragma unroll
      for (int of = 32; of; of >>= 1) ps += __shfl_xor(ps, of);
      lr[rr] = lr[rr] * alpha + ps; mr[rr] = mnew;
      o0[rr] *= alpha; o1[rr] *= alpha;
      pv4[rr] = p;
    }
    __syncthreads();
    {
      int j = tid >> 2, dc = (tid & 3) * 16;
      const float* vs = xv + ((size_t)((b * 1024 + t * 64 + j) * 8 + kvh)) * 128 + dc;
      #pragma unroll
      for (int i = 0; i < 16; i++){ TA[j][dc + i] = vs[i]; TB[j][dc + i] = vs[64 + i]; }
    }
    __syncthreads();
    for (int j = 0; j < 64; j++){
      float va = TA[j][ln], vb = TB[j][ln];
      float p0 = __shfl(pv4[0], j), p1 = __shfl(pv4[1], j);
      float p2 = __shfl(pv4[2], j), p3 = __shfl(pv4[3], j);
      o0[0] = fmaf(p0, va, o0[0]); o1[0] = fmaf(p0, vb, o1[0]);
      o0[1] = fmaf(p1, va, o0[1]); o1[1] = fmaf(p1, vb, o1[1]);
      o0[2] = fmaf(p2, va, o0[2]); o1[2] = fmaf(p2, vb, o1[2]);
      o0[3] = fmaf(p3, va, o0[3]); o1[3] = fmaf(p3, vb, o1[3]);
    }
  }
  #pragma unroll
  for (int rr = 0; rr < 4; rr++){
    int q = q0 + r0 + rr;
    float inv = 1.0f / lr[rr];
    size_t ob = ((size_t)(b * 1024 + q)) * 2048 + (size_t)h * 128;
    float v0 = o0[rr] * inv, v1 = o1[rr] * inv;
    bf16 h0 = __float2bfloat16(v0), h1 = __float2bfloat16(v1);
    ohi[ob + ln] = h0;      olo[ob + ln]      = __float2bfloat16(v0 - __bfloat162float(h0));
    ohi[ob + ln + 64] = h1; olo[ob + ln + 64] = __float2bfloat16(v1 - __bfloat162float(h1));
  }
}

// ---------------- small elementwise kernels ----------------
__global__ void resid_k(const int* __restrict__ flagp, const void* __restrict__ data,
                        const float* __restrict__ proj, float* __restrict__ d2, int n){
  int isf = flagp[0];
  int i = blockIdx.x * 256 + threadIdx.x;
  if (i >= n) return;
  d2[i] = ldin(data, i, isf) + proj[i];
}

__global__ void final_k(const int* __restrict__ flagp, const float* __restrict__ d2,
                        const float* __restrict__ moe, void* __restrict__ out, int n){
  int isf = flagp[0];
  int i = blockIdx.x * 256 + threadIdx.x;
  if (i >= n) return;
  float v = d2[i] + moe[i];
  if (isf) ((float*)out)[i] = v;
  else ((bf16*)out)[i] = __float2bfloat16(v);
}

// ---------------- dense per-row SwiGLU with LoRA deltas for expert e ----------------
__global__ __launch_bounds__(256) void sr_k(
    const int* __restrict__ flagp,
    const bf16* __restrict__ cw1, const bf16* __restrict__ cw3,
    const float* __restrict__ t1, const float* __restrict__ t3,
    const void* __restrict__ b1, const void* __restrict__ b3,
    int r0, int e, bf16* __restrict__ srh)
{
  int isf = flagp[0];
  int s = blockIdx.y;
  int col0 = blockIdx.x * 256;
  int tid = threadIdx.x;
  int row = r0 + s;
  __shared__ float sb1[16][256], sb3[16][256];
  __shared__ float st1[16], st3[16];
  for (int idx = tid; idx < 16 * 256; idx += 256){
    int r = idx >> 8; int c = idx & 255;
    sb1[r][c] = ldin(b1, ((size_t)e * 16 + r) * DFF + col0 + c, isf);
    sb3[r][c] = ldin(b3, ((size_t)e * 16 + r) * DFF + col0 + c, isf);
  }
  if (tid < 16){
    st1[tid] = t1[(size_t)row * 128 + e * 16 + tid];
    st3[tid] = t3[(size_t)row * 128 + e * 16 + tid];
  }
  __syncthreads();
  int j = col0 + tid;
  float x1 = __bfloat162float(cw1[(size_t)s * DFF + j]);
  float x3 = __bfloat162float(cw3[(size_t)s * DFF + j]);
  float l1 = 0.f, l3 = 0.f;
  #pragma unroll
  for (int r = 0; r < 16; r++){
    l1 = fmaf(st1[r], sb1[r][tid], l1);
    l3 = fmaf(st3[r], sb3[r][tid], l3);
  }
  x1 += 2.0f * l1; x3 += 2.0f * l3;
  float sig = 1.0f / (1.0f + __expf(-x1));
  srh[(size_t)s * DFF + j] = __float2bfloat16(x1 * sig * x3);
}

// ---------------- host ----------------
extern "C" void kernel_launch(void* const* d_in, const int* in_sizes, int n_in,
                              void* d_out, int out_size, void* d_ws, size_t ws_size,
                              hipStream_t stream) {
  (void)in_sizes; (void)n_in;
  const void* data   = d_in[0];
  const void* cosb   = d_in[2];
  const void* sinb   = d_in[3];
  const void* attn_w = d_in[4];
  const void* ffn_w  = d_in[5];
  const void* wq = d_in[6];
  const void* wk = d_in[7];
  const void* wvw = d_in[8];
  const void* wo = d_in[9];
  const void* qa = d_in[10];
  const void* qb = d_in[11];
  const void* ka = d_in[12];
  const void* kb = d_in[13];
  const void* va = d_in[14];
  const void* vb = d_in[15];
  const void* oa = d_in[16];
  const void* ob = d_in[17];
  const void* gate_w = d_in[18];
  const void* w1 = d_in[19];
  const void* w2 = d_in[20];
  const void* w3 = d_in[21];
  const void* a1 = d_in[22];
  const void* b1 = d_in[23];
  const void* a3 = d_in[24];
  const void* b3 = d_in[25];
  const void* a2 = d_in[26];
  const void* b2 = d_in[27];

  const int nElem = NT * DMODEL;
  dim3 blk(256);

  size_t need = ((size_t)81 << 20);
  if (ws_size < need){
    fill_b<<<(out_size + 255) / 256, blk, 0, stream>>>((bf16*)d_out,
        1000.0f + (float)(ws_size >> 20), out_size);
    return;
  }
  char* base = (char*)d_ws;
  float* data2 = (float*)(base);                       // [0,16) MB, persists
  float* accb  = (float*)(base + ((size_t)16 << 20));  // [16,32): attn proj -> moe acc
  bf16*  h_hi  = (bf16*)(base + ((size_t)32 << 20));   // [32,40): h hi -> o hi -> sn
  bf16*  h_lo  = (bf16*)(base + ((size_t)40 << 20));   // [40,48): h lo -> o lo -> phase-B smalls
  float* xq = (float*)(base + ((size_t)48 << 20));     // [48,64)
  float* xk = (float*)(base + ((size_t)64 << 20));     // [64,72)
  float* xv = (float*)(base + ((size_t)72 << 20));     // [72,80)
  int*   flag = (int*)(base + ((size_t)80 << 20));     // [80,80+4)
  // tq..to2 live in data2's last 1 MB (data2 written only after their last use)
  float* tq  = (float*)(base + ((size_t)15 << 20));
  float* tk  = tq + (size_t)NT * 16;
  float* tv  = tk + (size_t)NT * 16;
  float* to2 = tv + (size_t)NT * 16;
  // phase-B smalls in h_lo region
  float* t1 = (float*)(base + ((size_t)40 << 20));     // NT*128 f32 = 1 MB
  float* t3 = t1 + (size_t)NT * 128;                   // 1 MB
  float* logits = t3 + (size_t)NT * 128;               // 64 KB
  float* ew = logits + NT * 8;                         // 64 KB
  float* t2h = ew + NT * 8;                            // NH*16 f32 = 32 KB
  // phase-B big (reuse xq/xk/xv region)
  bf16* cw1h = (bf16*)(base + ((size_t)48 << 20));     // NH*DFF bf16 = 8 MB
  bf16* cw3h = (bf16*)(base + ((size_t)56 << 20));     // 8 MB
  bf16* srh  = (bf16*)(base + ((size_t)64 << 20));     // 8 MB
  bf16* sn = h_hi;

  detect_k<<<1, 64, 0, stream>>>(cosb, flag);

  // ---- attention block (fidelity via hi/lo split, 3-pass MFMA) ----
  rmsnorm_split<<<NT, blk, 0, stream>>>(flag, data, attn_w, h_hi, h_lo);
  gemm_k<<<dim3(32,1), blk, 0, stream>>>(flag, h_hi, h_lo, 2048, qa, 0, 16, tq, nullptr, 16,
      NT, 16, 2048, nullptr, 0, nullptr, 0, 0, nullptr, 0, 1, 2);
  gemm_k<<<dim3(32,1), blk, 0, stream>>>(flag, h_hi, h_lo, 2048, ka, 0, 16, tk, nullptr, 16,
      NT, 16, 2048, nullptr, 0, nullptr, 0, 0, nullptr, 0, 1, 2);
  gemm_k<<<dim3(32,1), blk, 0, stream>>>(flag, h_hi, h_lo, 2048, va, 0, 16, tv, nullptr, 16,
      NT, 16, 2048, nullptr, 0, nullptr, 0, 0, nullptr, 0, 1, 2);
  gemm_k<<<dim3(32,32), blk, 0, stream>>>(flag, h_hi, h_lo, 2048, wq, 0, 2048, xq, nullptr, 2048,
      NT, 2048, 2048, tq, 16, qb, 0, 2048, nullptr, 0, 1, 2);
  gemm_k<<<dim3(32,16), blk, 0, stream>>>(flag, h_hi, h_lo, 2048, wk, 0, 1024, xk, nullptr, 1024,
      NT, 1024, 2048, tk, 16, kb, 0, 1024, nullptr, 0, 1, 2);
  gemm_k<<<dim3(32,16), blk, 0, stream>>>(flag, h_hi, h_lo, 2048, wvw, 0, 1024, xv, nullptr, 1024,
      NT, 1024, 2048, tv, 16, vb, 0, 1024, nullptr, 0, 1, 2);
  rope_f32<<<8192, blk, 0, stream>>>(flag, xq, cosb, sinb, 16);
  rope_f32<<<4096, blk, 0, stream>>>(flag, xk, cosb, sinb, 8);
  flash_attn<<<2048, blk, 0, stream>>>(xq, xk, xv, h_hi, h_lo);   // o -> h_hi/h_lo
  gemm_k<<<dim3(32,1), blk, 0, stream>>>(flag, h_hi, h_lo, 2048, oa, 0, 16, to2, nullptr, 16,
      NT, 16, 2048, nullptr, 0, nullptr, 0, 0, nullptr, 0, 1, 2);
  gemm_k<<<dim3(32,32), blk, 0, stream>>>(flag, h_hi, h_lo, 2048, wo, 0, 2048, accb, nullptr, 2048,
      NT, 2048, 2048, to2, 16, ob, 0, 2048, nullptr, 0, 1, 2);
  resid_k<<<(nElem + 255) / 256, blk, 0, stream>>>(flag, data, accb, data2, nElem);

  // ---- MoE prep ----
  rmsnorm_f32<<<NT, blk, 0, stream>>>(flag, data2, ffn_w, sn);
  logits_k<<<NT, blk, 0, stream>>>(flag, data2, ffn_w, gate_w, logits);
  route_ew<<<8, blk, 0, stream>>>(logits, ew);
  zero_f<<<(nElem + 255) / 256, blk, 0, stream>>>(accb, nElem);
  for (int e = 0; e < 8; e++){
    gemm_k<<<dim3(32,1), blk, 0, stream>>>(flag, sn, nullptr, 2048, a1, (long long)e * 2048 * 16, 16,
        t1 + e * 16, nullptr, 128, NT, 16, 2048, nullptr, 0, nullptr, 0, 0, nullptr, 0, 1, 0);
    gemm_k<<<dim3(32,1), blk, 0, stream>>>(flag, sn, nullptr, 2048, a3, (long long)e * 2048 * 16, 16,
        t3 + e * 16, nullptr, 128, NT, 16, 2048, nullptr, 0, nullptr, 0, 0, nullptr, 0, 1, 0);
  }

  // ---- dense MoE in 4 quarters of NH=512 rows ----
  for (int hf = 0; hf < 4; hf++){
    int r0 = hf * NH;
    gemm_k<<<dim3(8,128), blk, 0, stream>>>(flag, sn + (size_t)r0 * 2048, nullptr, 2048, w1, 0, 8192,
        nullptr, cw1h, 8192, NH, 8192, 2048, nullptr, 0, nullptr, 0, 0, nullptr, 0, 0, 0);
    gemm_k<<<dim3(8,128), blk, 0, stream>>>(flag, sn + (size_t)r0 * 2048, nullptr, 2048, w3, 0, 8192,
        nullptr, cw3h, 8192, NH, 8192, 2048, nullptr, 0, nullptr, 0, 0, nullptr, 0, 0, 0);
    for (int e = 0; e < 8; e++){
      sr_k<<<dim3(32, NH), blk, 0, stream>>>(flag, cw1h, cw3h, t1, t3, b1, b3, r0, e, srh);
      gemm_k<<<dim3(8,1), blk, 0, stream>>>(flag, srh, nullptr, 8192, a2, (long long)e * 8192 * 16, 16,
          t2h, nullptr, 16, NH, 16, 8192, nullptr, 0, nullptr, 0, 0, nullptr, 0, 1, 0);
      gemm_k<<<dim3(8,32), blk, 0, stream>>>(flag, srh, nullptr, 8192, w2, 0, 2048,
          accb + (size_t)r0 * 2048, nullptr, 2048, NH, 2048, 8192,
          t2h, 16, b2, (long long)e * 16 * 2048, 2048, ew + (size_t)r0 * 8, e, 2, 0);
    }
  }
  final_k<<<(nElem + 255) / 256, blk, 0, stream>>>(flag, data2, accb, d_out, nElem);
}